// Round 2
// baseline (1834.637 us; speedup 1.0000x reference)
//
#include <hip/hip_runtime.h>

#define GRID 64
#define NVOX (GRID * GRID * GRID)   // 262144
#define NBLK 256                    // voxel-walker blocks, 1024 voxels each

typedef float f32x2 __attribute__((ext_vector_type(2)));

// Packed v2f32 global atomic fadd (gfx90a+ family instruction). Guarded:
// falls back to two scalar hw fadds (proven path from round 0/1).
__device__ __forceinline__ void pk_fadd(float* a, float x, float y) {
#if __has_builtin(__builtin_amdgcn_global_atomic_fadd_v2f32)
    f32x2 v = {x, y};
    __builtin_amdgcn_global_atomic_fadd_v2f32((f32x2*)a, v);
#elif __has_builtin(__builtin_amdgcn_flat_atomic_fadd_v2f32)
    f32x2 v = {x, y};
    __builtin_amdgcn_flat_atomic_fadd_v2f32((f32x2*)a, v);
#else
    atomicAdd(a, x);
    atomicAdd(a + 1, y);
#endif
}

// ---- scatter: 4 packed atomics per point into replicated [R][NVOX][8] table
__global__ void dv_scatter(const float* __restrict__ points,
                           const int* __restrict__ gi,
                           int n, float* __restrict__ acc, int rmask) {
    int i = blockIdx.x * blockDim.x + threadIdx.x;
    if (i >= n) return;
    int g0 = gi[3 * i + 0];
    int g1 = gi[3 * i + 1];
    int g2 = gi[3 * i + 2];
    int lin = (g0 << 12) | (g1 << 6) | g2;
    int rep = blockIdx.x & rmask;
    float* b = acc + (((size_t)rep << 18) + (size_t)lin) * 8;
    const float* p = points + (size_t)i * 7;
    float p0 = p[0], p1 = p[1], p2 = p[2], p3 = p[3];
    float p4 = p[4], p5 = p[5], p6 = p[6];
    pk_fadd(b + 0, p0, p1);
    pk_fadd(b + 2, p2, p3);
    pk_fadd(b + 4, p4, p5);
    pk_fadd(b + 6, p6, 1.0f);   // count carried as float in slot 7
}

// ---- per-block occupied-voxel counts (flags from summed slot-7 counts) ----
__global__ void dv_blocksum(const float* __restrict__ acc, int R,
                            int* __restrict__ blockSums) {
    int b = blockIdx.x, t = threadIdx.x;
    int flags = 0;
#pragma unroll
    for (int j = 0; j < 4; ++j) {
        int v = b * 1024 + t * 4 + j;
        float c = 0.f;
        for (int r = 0; r < R; ++r)
            c += acc[(((size_t)r << 18) + (size_t)v) * 8 + 7];
        flags += (c > 0.f) ? 1 : 0;
    }
    __shared__ int sm[256];
    sm[t] = flags;
    __syncthreads();
    for (int off = 128; off > 0; off >>= 1) {
        if (t < off) sm[t] += sm[t + off];
        __syncthreads();
    }
    if (t == 0) blockSums[b] = sm[0];
}

// ---- exclusive scan of 256 block sums (one block) --------------------------
__global__ void dv_scanblocks(const int* __restrict__ blockSums,
                              int* __restrict__ blockOffs,
                              int* __restrict__ nUnique) {
    __shared__ int sm[NBLK];
    int t = threadIdx.x;
    int mine = blockSums[t];
    sm[t] = mine;
    __syncthreads();
    for (int off = 1; off < NBLK; off <<= 1) {
        int v = (t >= off) ? sm[t - off] : 0;
        __syncthreads();
        sm[t] += v;
        __syncthreads();
    }
    blockOffs[t] = sm[t] - mine;
    if (t == NBLK - 1) *nUnique = sm[t];
}

// ---- reduce replicas + emit compacted means + coords -----------------------
__global__ void dv_emit(const float* __restrict__ acc, int R,
                        const int* __restrict__ blockOffs,
                        float* __restrict__ out_mean,
                        float* __restrict__ out_coords) {
    int b = blockIdx.x, t = threadIdx.x;
    float s[4][8];
    int base = b * 1024 + t * 4;
#pragma unroll
    for (int j = 0; j < 4; ++j) {
#pragma unroll
        for (int k = 0; k < 8; ++k) s[j][k] = 0.f;
        int v = base + j;
        for (int r = 0; r < R; ++r) {
            const float4* row =
                (const float4*)(acc + (((size_t)r << 18) + (size_t)v) * 8);
            float4 lo = row[0], hi = row[1];
            s[j][0] += lo.x; s[j][1] += lo.y; s[j][2] += lo.z; s[j][3] += lo.w;
            s[j][4] += hi.x; s[j][5] += hi.y; s[j][6] += hi.z; s[j][7] += hi.w;
        }
    }
    int pre[4], mycount = 0;
#pragma unroll
    for (int j = 0; j < 4; ++j) {
        pre[j] = mycount;
        mycount += (s[j][7] > 0.f) ? 1 : 0;
    }
    __shared__ int sm[256];
    sm[t] = mycount;
    __syncthreads();
    for (int off = 1; off < 256; off <<= 1) {
        int v = (t >= off) ? sm[t - off] : 0;
        __syncthreads();
        sm[t] += v;
        __syncthreads();
    }
    int rank0 = blockOffs[b] + (sm[t] - mycount);
#pragma unroll
    for (int j = 0; j < 4; ++j) {
        if (s[j][7] > 0.f) {
            int r = rank0 + pre[j];
            int v = base + j;
            float inv = 1.0f / s[j][7];
            float* m = out_mean + (size_t)r * 7;
#pragma unroll
            for (int k = 0; k < 7; ++k) m[k] = s[j][k] * inv;
            float* cd = out_coords + (size_t)r * 3;
            cd[0] = (float)(v >> 12);
            cd[1] = (float)((v >> 6) & 63);
            cd[2] = (float)(v & 63);
        }
    }
}

// ---- vectorized padding fill (d_out re-poisoned before every call) ---------
__global__ void dv_fill(const int* __restrict__ nuP, float* __restrict__ out,
                        int n) {
    int nu = *nuP;
    size_t meanChunks = (size_t)n * 7 / 4;   // n*7 divisible by 4 (n=4M)
    size_t coordChunks = (size_t)n * 3 / 4;
    size_t total = meanChunks + coordChunks;
    size_t i = (size_t)blockIdx.x * blockDim.x + threadIdx.x;
    if (i >= total) return;
    float* mean = out;
    float* coords = out + (size_t)n * 7;
    if (i < meanChunks) {
        size_t base = i * 4, lim = (size_t)nu * 7;
        if (base >= lim) {
            *(float4*)(mean + base) = make_float4(0.f, 0.f, 0.f, 0.f);
        } else if (base + 4 > lim) {
            for (size_t k = lim; k < base + 4; ++k) mean[k] = 0.f;
        }
    } else {
        size_t base = (i - meanChunks) * 4, lim = (size_t)nu * 3;
        if (base >= lim) {
            *(float4*)(coords + base) = make_float4(-1.f, -1.f, -1.f, -1.f);
        } else if (base + 4 > lim) {
            for (size_t k = lim; k < base + 4; ++k) coords[k] = -1.f;
        }
    }
}

extern "C" void kernel_launch(void* const* d_in, const int* in_sizes, int n_in,
                              void* d_out, int out_size, void* d_ws, size_t ws_size,
                              hipStream_t stream) {
    const float* points = (const float*)d_in[0];
    const int*   gi     = (const int*)d_in[1];
    int n = in_sizes[0] / 7;   // 4,000,000

    // replica count chosen from workspace size (constant across calls)
    size_t accBytes1 = (size_t)NVOX * 8 * sizeof(float);   // 8 MB per replica
    int R = 1;
    if (ws_size >= 4 * accBytes1 + 4096) R = 4;
    else if (ws_size >= 2 * accBytes1 + 4096) R = 2;

    float* acc = (float*)d_ws;
    int* meta = (int*)((char*)d_ws + (size_t)R * accBytes1);
    int* blockSums = meta;
    int* blockOffs = meta + NBLK;
    int* nUnique   = meta + 2 * NBLK;

    float* out_mean   = (float*)d_out;                   // [n, 7]
    float* out_coords = (float*)d_out + (size_t)n * 7;   // [n, 3]

    hipMemsetAsync(d_ws, 0, (size_t)R * accBytes1, stream);

    int threads = 256;
    int blocksN = (n + threads - 1) / threads;
    dv_scatter<<<blocksN, threads, 0, stream>>>(points, gi, n, acc, R - 1);
    dv_blocksum<<<NBLK, 256, 0, stream>>>(acc, R, blockSums);
    dv_scanblocks<<<1, NBLK, 0, stream>>>(blockSums, blockOffs, nUnique);
    dv_emit<<<NBLK, 256, 0, stream>>>(acc, R, blockOffs, out_mean, out_coords);

    size_t fillChunks = (size_t)n * 7 / 4 + (size_t)n * 3 / 4;
    int fillBlocks = (int)((fillChunks + threads - 1) / threads);
    dv_fill<<<fillBlocks, threads, 0, stream>>>(nUnique, (float*)d_out, n);
}

// Round 3
// 571.873 us; speedup vs baseline: 3.2081x; 3.2081x over previous
//
#include <hip/hip_runtime.h>

#define NVOX 262144     // 64^3
#define NBLK 256        // voxel-walker blocks, 1024 voxels each

struct Meta {
    unsigned blockSums[NBLK];      // per-block point counts
    unsigned blockFlagSums[NBLK];  // per-block occupied-voxel counts
    unsigned blockOffs[NBLK];      // exclusive scan of blockSums
    unsigned blockRankOffs[NBLK];  // exclusive scan of blockFlagSums
    unsigned nUnique;
};

// ---- pass A: per-voxel count + per-point slot (the ONLY global atomics) ----
__global__ void dv_count(const int* __restrict__ gi, int n,
                         unsigned* __restrict__ counts,
                         unsigned short* __restrict__ slots) {
    int i = blockIdx.x * blockDim.x + threadIdx.x;
    if (i >= n) return;
    int lin = (gi[3 * i] << 12) | (gi[3 * i + 1] << 6) | gi[3 * i + 2];
    unsigned s = atomicAdd(&counts[lin], 1u);
    slots[i] = (unsigned short)s;   // max points/voxel ~50 for this input
}

// ---- pass B1: per-block sums of counts and occupied flags ------------------
__global__ void dv_bs1(const unsigned* __restrict__ counts,
                       Meta* __restrict__ meta) {
    int b = blockIdx.x, t = threadIdx.x;
    uint4 c = ((const uint4*)(counts + (size_t)b * 1024))[t];
    unsigned cs = c.x + c.y + c.z + c.w;
    unsigned fs = (c.x > 0) + (c.y > 0) + (c.z > 0) + (c.w > 0);
    __shared__ unsigned smC[256], smF[256];
    smC[t] = cs; smF[t] = fs;
    __syncthreads();
    for (int off = 128; off > 0; off >>= 1) {
        if (t < off) { smC[t] += smC[t + off]; smF[t] += smF[t + off]; }
        __syncthreads();
    }
    if (t == 0) { meta->blockSums[b] = smC[0]; meta->blockFlagSums[b] = smF[0]; }
}

// ---- pass B2: exclusive scan of the 256 block sums (one block) -------------
__global__ void dv_scan2(unsigned* __restrict__ offsets, int n,
                         Meta* __restrict__ meta) {
    __shared__ unsigned smC[NBLK], smF[NBLK];
    int t = threadIdx.x;
    unsigned c = meta->blockSums[t], f = meta->blockFlagSums[t];
    smC[t] = c; smF[t] = f;
    __syncthreads();
    for (int off = 1; off < NBLK; off <<= 1) {
        unsigned vc = (t >= off) ? smC[t - off] : 0u;
        unsigned vf = (t >= off) ? smF[t - off] : 0u;
        __syncthreads();
        smC[t] += vc; smF[t] += vf;
        __syncthreads();
    }
    meta->blockOffs[t] = smC[t] - c;
    meta->blockRankOffs[t] = smF[t] - f;
    if (t == NBLK - 1) { meta->nUnique = smF[t]; offsets[NVOX] = (unsigned)n; }
}

// ---- pass B3: block-local scan -> in-place counts -> exclusive offsets -----
__global__ void dv_scan3(unsigned* __restrict__ counts,
                         const Meta* __restrict__ meta) {
    int b = blockIdx.x, t = threadIdx.x;
    uint4 c = ((const uint4*)(counts + (size_t)b * 1024))[t];
    unsigned mysum = c.x + c.y + c.z + c.w;
    __shared__ unsigned sm[256];
    sm[t] = mysum;
    __syncthreads();
    for (int off = 1; off < 256; off <<= 1) {
        unsigned v = (t >= off) ? sm[t - off] : 0u;
        __syncthreads();
        sm[t] += v;
        __syncthreads();
    }
    unsigned base = meta->blockOffs[b] + sm[t] - mysum;
    uint4 o;
    o.x = base;
    o.y = base + c.x;
    o.z = o.y + c.y;
    o.w = o.z + c.z;
    ((uint4*)(counts + (size_t)b * 1024))[t] = o;
}

// ---- pass C: atomic-free scatter of point indices into sorted order --------
__global__ void dv_scatter2(const int* __restrict__ gi, int n,
                            const unsigned* __restrict__ offsets,
                            const unsigned short* __restrict__ slots,
                            unsigned* __restrict__ perm) {
    int i = blockIdx.x * blockDim.x + threadIdx.x;
    if (i >= n) return;
    int lin = (gi[3 * i] << 12) | (gi[3 * i + 1] << 6) | gi[3 * i + 2];
    perm[offsets[lin] + (unsigned)slots[i]] = (unsigned)i;
}

// ---- pass D: per-voxel gather-reduce, emit compacted means + coords --------
__global__ void dv_emit2(const float* __restrict__ points,
                         const unsigned* __restrict__ offsets,
                         const unsigned* __restrict__ perm,
                         const Meta* __restrict__ meta,
                         float* __restrict__ out_mean,
                         float* __restrict__ out_coords) {
    int b = blockIdx.x, t = threadIdx.x;
    int base = b * 1024 + t * 4;
    uint4 o4 = ((const uint4*)offsets)[b * 256 + t];
    unsigned o[5];
    o[0] = o4.x; o[1] = o4.y; o[2] = o4.z; o[3] = o4.w;
    o[4] = offsets[base + 4];   // offsets[NVOX] valid (=n)
    int c[4], pre[4], mycount = 0;
#pragma unroll
    for (int j = 0; j < 4; ++j) {
        c[j] = (int)(o[j + 1] - o[j]);
        pre[j] = mycount;
        mycount += (c[j] > 0) ? 1 : 0;
    }
    __shared__ int sm[256];
    sm[t] = mycount;
    __syncthreads();
    for (int off = 1; off < 256; off <<= 1) {
        int v = (t >= off) ? sm[t - off] : 0;
        __syncthreads();
        sm[t] += v;
        __syncthreads();
    }
    int rank0 = (int)meta->blockRankOffs[b] + (sm[t] - mycount);
#pragma unroll
    for (int j = 0; j < 4; ++j) {
        if (c[j] > 0) {
            float s0 = 0.f, s1 = 0.f, s2 = 0.f, s3 = 0.f,
                  s4 = 0.f, s5 = 0.f, s6 = 0.f;
            for (unsigned k = o[j]; k < o[j + 1]; ++k) {
                unsigned idx = perm[k];
                const float* p = points + (size_t)idx * 7;
                s0 += p[0]; s1 += p[1]; s2 += p[2]; s3 += p[3];
                s4 += p[4]; s5 += p[5]; s6 += p[6];
            }
            int r = rank0 + pre[j];
            int v = base + j;
            float inv = 1.0f / (float)c[j];
            float* m = out_mean + (size_t)r * 7;
            m[0] = s0 * inv; m[1] = s1 * inv; m[2] = s2 * inv;
            m[3] = s3 * inv; m[4] = s4 * inv; m[5] = s5 * inv;
            m[6] = s6 * inv;
            float* cd = out_coords + (size_t)r * 3;
            cd[0] = (float)(v >> 12);
            cd[1] = (float)((v >> 6) & 63);
            cd[2] = (float)(v & 63);
        }
    }
}

// ---- vectorized padding fill (d_out re-poisoned before every call) ---------
__global__ void dv_fill(const unsigned* __restrict__ nuP,
                        float* __restrict__ out, int n) {
    int nu = (int)*nuP;
    size_t meanChunks = (size_t)n * 7 / 4;
    size_t coordChunks = (size_t)n * 3 / 4;
    size_t total = meanChunks + coordChunks;
    size_t i = (size_t)blockIdx.x * blockDim.x + threadIdx.x;
    if (i >= total) return;
    float* mean = out;
    float* coords = out + (size_t)n * 7;
    if (i < meanChunks) {
        size_t base = i * 4, lim = (size_t)nu * 7;
        if (base >= lim) {
            *(float4*)(mean + base) = make_float4(0.f, 0.f, 0.f, 0.f);
        } else if (base + 4 > lim) {
            for (size_t k = lim; k < base + 4; ++k) mean[k] = 0.f;
        }
    } else {
        size_t base = (i - meanChunks) * 4, lim = (size_t)nu * 3;
        if (base >= lim) {
            *(float4*)(coords + base) = make_float4(-1.f, -1.f, -1.f, -1.f);
        } else if (base + 4 > lim) {
            for (size_t k = lim; k < base + 4; ++k) coords[k] = -1.f;
        }
    }
}

extern "C" void kernel_launch(void* const* d_in, const int* in_sizes, int n_in,
                              void* d_out, int out_size, void* d_ws, size_t ws_size,
                              hipStream_t stream) {
    const float* points = (const float*)d_in[0];
    const int*   gi     = (const int*)d_in[1];
    int n = in_sizes[0] / 7;   // 4,000,000

    // workspace layout (~25.2 MB total)
    char* w = (char*)d_ws;
    unsigned*       perm    = (unsigned*)w;                       // 16 MB
    unsigned short* slots   = (unsigned short*)(w + (size_t)n * 4);       // 8 MB
    unsigned*       offsets = (unsigned*)(w + (size_t)n * 4 + (size_t)n * 2); // (NVOX+4)*4
    Meta*           meta    = (Meta*)((char*)offsets + (size_t)(NVOX + 4) * 4);

    float* out_mean   = (float*)d_out;                   // [n, 7]
    float* out_coords = (float*)d_out + (size_t)n * 7;   // [n, 3]

    // zero only the counts table
    hipMemsetAsync(offsets, 0, (size_t)(NVOX + 4) * 4, stream);

    int threads = 256;
    int blocksN = (n + threads - 1) / threads;
    dv_count<<<blocksN, threads, 0, stream>>>(gi, n, offsets, slots);
    dv_bs1<<<NBLK, 256, 0, stream>>>(offsets, meta);
    dv_scan2<<<1, NBLK, 0, stream>>>(offsets, n, meta);
    dv_scan3<<<NBLK, 256, 0, stream>>>(offsets, meta);
    dv_scatter2<<<blocksN, threads, 0, stream>>>(gi, n, offsets, slots, perm);
    dv_emit2<<<NBLK, 256, 0, stream>>>(points, offsets, perm, meta,
                                       out_mean, out_coords);

    size_t fillChunks = (size_t)n * 7 / 4 + (size_t)n * 3 / 4;
    int fillBlocks = (int)((fillChunks + threads - 1) / threads);
    dv_fill<<<fillBlocks, threads, 0, stream>>>(&meta->nUnique,
                                                (float*)d_out, n);
}

// Round 4
// 567.762 us; speedup vs baseline: 3.2313x; 1.0072x over previous
//
#include <hip/hip_runtime.h>

#define NVOX 262144     // 64^3
#define NB   256        // buckets = top 8 bits of lin
#define VPB  1024       // voxels per bucket = low 10 bits
#define PPB  2048       // points per block in binning passes
#define NBLK 256        // fallback voxel-walker blocks

// ======================= shared: padding fill ===============================
__global__ void dv_fill(const unsigned* __restrict__ nuP,
                        float* __restrict__ out, int n) {
    int nu = (int)*nuP;
    size_t meanChunks = (size_t)n * 7 / 4;
    size_t coordChunks = (size_t)n * 3 / 4;
    size_t total = meanChunks + coordChunks;
    size_t i = (size_t)blockIdx.x * blockDim.x + threadIdx.x;
    if (i >= total) return;
    float* mean = out;
    float* coords = out + (size_t)n * 7;
    if (i < meanChunks) {
        size_t base = i * 4, lim = (size_t)nu * 7;
        if (base >= lim) {
            *(float4*)(mean + base) = make_float4(0.f, 0.f, 0.f, 0.f);
        } else if (base + 4 > lim) {
            for (size_t k = lim; k < base + 4; ++k) mean[k] = 0.f;
        }
    } else {
        size_t base = (i - meanChunks) * 4, lim = (size_t)nu * 3;
        if (base >= lim) {
            *(float4*)(coords + base) = make_float4(-1.f, -1.f, -1.f, -1.f);
        } else if (base + 4 > lim) {
            for (size_t k = lim; k < base + 4; ++k) coords[k] = -1.f;
        }
    }
}

// ======================= RADIX (fat-record) PATH ============================
// P1: per-block LDS histogram over 256 buckets (coalesced global write)
__global__ void rx_hist(const int* __restrict__ gi, int n,
                        unsigned* __restrict__ blockHist) {
    __shared__ unsigned h[NB];
    int t = threadIdx.x, b = blockIdx.x;
    h[t] = 0;
    __syncthreads();
    int base = b * PPB;
#pragma unroll
    for (int k = 0; k < PPB / 256; ++k) {
        int i = base + k * 256 + t;
        if (i < n) {
            int g0 = gi[3 * i], g1 = gi[3 * i + 1];
            atomicAdd(&h[(g0 << 2) | (g1 >> 4)], 1u);
        }
    }
    __syncthreads();
    blockHist[(size_t)b * NB + t] = h[t];
}

// P2a: per-bucket totals (one block per bucket)
__global__ void rx_bucketsum(const unsigned* __restrict__ blockHist, int nb1,
                             unsigned* __restrict__ bucketCount) {
    int bk = blockIdx.x, t = threadIdx.x;
    unsigned s = 0;
    for (int blk = t; blk < nb1; blk += 256) s += blockHist[(size_t)blk * NB + bk];
    __shared__ unsigned sm[256];
    sm[t] = s;
    __syncthreads();
    for (int off = 128; off > 0; off >>= 1) {
        if (t < off) sm[t] += sm[t + off];
        __syncthreads();
    }
    if (t == 0) bucketCount[bk] = sm[0];
}

// P2b / P5: exclusive scan of 256 values; out[256] = total
__global__ void rx_scan256(const unsigned* __restrict__ in,
                           unsigned* __restrict__ out) {
    __shared__ unsigned sm[NB];
    int t = threadIdx.x;
    unsigned mine = in[t];
    sm[t] = mine;
    __syncthreads();
    for (int off = 1; off < NB; off <<= 1) {
        unsigned v = (t >= off) ? sm[t - off] : 0u;
        __syncthreads();
        sm[t] += v;
        __syncthreads();
    }
    out[t] = sm[t] - mine;
    if (t == NB - 1) out[NB] = sm[t];
}

// P2c: per-bucket exclusive scan over block hists (in place, + bucketBase)
__global__ void rx_blockscan(unsigned* __restrict__ blockHist, int nb1,
                             const unsigned* __restrict__ bucketBase) {
    int bk = blockIdx.x, t = threadIdx.x;
    __shared__ unsigned sm[256];
    __shared__ unsigned carry;
    if (t == 0) carry = bucketBase[bk];
    __syncthreads();
    for (int chunk = 0; chunk * 256 < nb1; ++chunk) {
        int blk = chunk * 256 + t;
        unsigned v = (blk < nb1) ? blockHist[(size_t)blk * NB + bk] : 0u;
        sm[t] = v;
        __syncthreads();
        for (int off = 1; off < 256; off <<= 1) {
            unsigned u = (t >= off) ? sm[t - off] : 0u;
            __syncthreads();
            sm[t] += u;
            __syncthreads();
        }
        if (blk < nb1) blockHist[(size_t)blk * NB + bk] = carry + sm[t] - v;
        __syncthreads();
        if (t == 255) carry += sm[255];
        __syncthreads();
    }
}

// P3: fat scatter — write 32B records {p0..p6, sub} to per-(block,bucket) runs
__global__ void rx_scatter(const int* __restrict__ gi,
                           const float* __restrict__ pts, int n,
                           const unsigned* __restrict__ blockHist,
                           float* __restrict__ recs) {
    __shared__ unsigned runBase[NB];
    int t = threadIdx.x, b = blockIdx.x;
    runBase[t] = blockHist[(size_t)b * NB + t];
    __syncthreads();
    int base = b * PPB;
#pragma unroll
    for (int k = 0; k < PPB / 256; ++k) {
        int i = base + k * 256 + t;
        if (i < n) {
            int g0 = gi[3 * i], g1 = gi[3 * i + 1], g2 = gi[3 * i + 2];
            int bk = (g0 << 2) | (g1 >> 4);
            unsigned sub = (unsigned)(((g1 & 15) << 6) | g2);
            unsigned dst = atomicAdd(&runBase[bk], 1u);
            const float* p = pts + (size_t)i * 7;
            float4 r0 = make_float4(p[0], p[1], p[2], p[3]);
            float4 r1 = make_float4(p[4], p[5], p[6], __uint_as_float(sub));
            float4* r = (float4*)(recs + (size_t)dst * 8);
            r[0] = r0;
            r[1] = r1;
        }
    }
}

// P4: per-bucket LDS accumulation (stride-9 pad), write accTable + occ counts
__global__ void __launch_bounds__(256) rx_accum(
        const float* __restrict__ recs,
        const unsigned* __restrict__ bucketBase,
        float* __restrict__ accTable, unsigned* __restrict__ occCount) {
    __shared__ float acc[VPB * 9];   // 36 KB
    int t = threadIdx.x, bk = blockIdx.x;
    for (int k = t; k < VPB * 9; k += 256) acc[k] = 0.f;
    __syncthreads();
    unsigned s = bucketBase[bk], e = bucketBase[bk + 1];
    for (unsigned i = s + t; i < e; i += 256) {
        const float4* r = (const float4*)(recs + (size_t)i * 8);
        float4 r0 = r[0], r1 = r[1];
        unsigned sub = __float_as_uint(r1.w);
        float* a = acc + sub * 9;
        atomicAdd(a + 0, r0.x); atomicAdd(a + 1, r0.y);
        atomicAdd(a + 2, r0.z); atomicAdd(a + 3, r0.w);
        atomicAdd(a + 4, r1.x); atomicAdd(a + 5, r1.y);
        atomicAdd(a + 6, r1.z); atomicAdd(a + 7, 1.0f);
    }
    __syncthreads();
    unsigned occ = 0;
#pragma unroll
    for (int k = 0; k < 4; ++k) {
        int v = k * 256 + t;
        float c = acc[v * 9 + 7];
        occ += (c > 0.f) ? 1u : 0u;
        float4* o = (float4*)(accTable + ((size_t)bk * VPB + v) * 8);
        o[0] = make_float4(acc[v * 9 + 0], acc[v * 9 + 1],
                           acc[v * 9 + 2], acc[v * 9 + 3]);
        o[1] = make_float4(acc[v * 9 + 4], acc[v * 9 + 5],
                           acc[v * 9 + 6], c);
    }
    __shared__ unsigned sm[256];
    sm[t] = occ;
    __syncthreads();
    for (int off = 128; off > 0; off >>= 1) {
        if (t < off) sm[t] += sm[t + off];
        __syncthreads();
    }
    if (t == 0) occCount[bk] = sm[0];
}

// P6: emit compacted means + coords from accTable
__global__ void rx_emit(const float* __restrict__ accTable,
                        const unsigned* __restrict__ rankBase,
                        float* __restrict__ out_mean,
                        float* __restrict__ out_coords) {
    int bk = blockIdx.x, t = threadIdx.x;
    float row[4][8];
    int pre[4], mycount = 0;
#pragma unroll
    for (int j = 0; j < 4; ++j) {
        int v = t * 4 + j;
        const float4* a = (const float4*)(accTable + ((size_t)bk * VPB + v) * 8);
        float4 r0 = a[0], r1 = a[1];
        row[j][0] = r0.x; row[j][1] = r0.y; row[j][2] = r0.z; row[j][3] = r0.w;
        row[j][4] = r1.x; row[j][5] = r1.y; row[j][6] = r1.z; row[j][7] = r1.w;
        pre[j] = mycount;
        mycount += (row[j][7] > 0.f) ? 1 : 0;
    }
    __shared__ int sm[256];
    sm[t] = mycount;
    __syncthreads();
    for (int off = 1; off < 256; off <<= 1) {
        int v = (t >= off) ? sm[t - off] : 0;
        __syncthreads();
        sm[t] += v;
        __syncthreads();
    }
    int rank0 = (int)rankBase[bk] + (sm[t] - mycount);
#pragma unroll
    for (int j = 0; j < 4; ++j) {
        if (row[j][7] > 0.f) {
            int r = rank0 + pre[j];
            int lin = (bk << 10) | (t * 4 + j);
            float inv = 1.0f / row[j][7];
            float* m = out_mean + (size_t)r * 7;
#pragma unroll
            for (int k = 0; k < 7; ++k) m[k] = row[j][k] * inv;
            float* cd = out_coords + (size_t)r * 3;
            cd[0] = (float)(lin >> 12);
            cd[1] = (float)((lin >> 6) & 63);
            cd[2] = (float)(lin & 63);
        }
    }
}

// ======================= FALLBACK PATH (round-3, proven) ====================
struct Meta {
    unsigned blockSums[NBLK];
    unsigned blockFlagSums[NBLK];
    unsigned blockOffs[NBLK];
    unsigned blockRankOffs[NBLK];
    unsigned nUnique;
};

__global__ void dv_count(const int* __restrict__ gi, int n,
                         unsigned* __restrict__ counts,
                         unsigned short* __restrict__ slots) {
    int i = blockIdx.x * blockDim.x + threadIdx.x;
    if (i >= n) return;
    int lin = (gi[3 * i] << 12) | (gi[3 * i + 1] << 6) | gi[3 * i + 2];
    unsigned s = atomicAdd(&counts[lin], 1u);
    slots[i] = (unsigned short)s;
}

__global__ void dv_bs1(const unsigned* __restrict__ counts,
                       Meta* __restrict__ meta) {
    int b = blockIdx.x, t = threadIdx.x;
    uint4 c = ((const uint4*)(counts + (size_t)b * 1024))[t];
    unsigned cs = c.x + c.y + c.z + c.w;
    unsigned fs = (c.x > 0) + (c.y > 0) + (c.z > 0) + (c.w > 0);
    __shared__ unsigned smC[256], smF[256];
    smC[t] = cs; smF[t] = fs;
    __syncthreads();
    for (int off = 128; off > 0; off >>= 1) {
        if (t < off) { smC[t] += smC[t + off]; smF[t] += smF[t + off]; }
        __syncthreads();
    }
    if (t == 0) { meta->blockSums[b] = smC[0]; meta->blockFlagSums[b] = smF[0]; }
}

__global__ void dv_scan2(unsigned* __restrict__ offsets, int n,
                         Meta* __restrict__ meta) {
    __shared__ unsigned smC[NBLK], smF[NBLK];
    int t = threadIdx.x;
    unsigned c = meta->blockSums[t], f = meta->blockFlagSums[t];
    smC[t] = c; smF[t] = f;
    __syncthreads();
    for (int off = 1; off < NBLK; off <<= 1) {
        unsigned vc = (t >= off) ? smC[t - off] : 0u;
        unsigned vf = (t >= off) ? smF[t - off] : 0u;
        __syncthreads();
        smC[t] += vc; smF[t] += vf;
        __syncthreads();
    }
    meta->blockOffs[t] = smC[t] - c;
    meta->blockRankOffs[t] = smF[t] - f;
    if (t == NBLK - 1) { meta->nUnique = smF[t]; offsets[NVOX] = (unsigned)n; }
}

__global__ void dv_scan3(unsigned* __restrict__ counts,
                         const Meta* __restrict__ meta) {
    int b = blockIdx.x, t = threadIdx.x;
    uint4 c = ((const uint4*)(counts + (size_t)b * 1024))[t];
    unsigned mysum = c.x + c.y + c.z + c.w;
    __shared__ unsigned sm[256];
    sm[t] = mysum;
    __syncthreads();
    for (int off = 1; off < 256; off <<= 1) {
        unsigned v = (t >= off) ? sm[t - off] : 0u;
        __syncthreads();
        sm[t] += v;
        __syncthreads();
    }
    unsigned base = meta->blockOffs[b] + sm[t] - mysum;
    uint4 o;
    o.x = base;
    o.y = base + c.x;
    o.z = o.y + c.y;
    o.w = o.z + c.z;
    ((uint4*)(counts + (size_t)b * 1024))[t] = o;
}

__global__ void dv_scatter2(const int* __restrict__ gi, int n,
                            const unsigned* __restrict__ offsets,
                            const unsigned short* __restrict__ slots,
                            unsigned* __restrict__ perm) {
    int i = blockIdx.x * blockDim.x + threadIdx.x;
    if (i >= n) return;
    int lin = (gi[3 * i] << 12) | (gi[3 * i + 1] << 6) | gi[3 * i + 2];
    perm[offsets[lin] + (unsigned)slots[i]] = (unsigned)i;
}

__global__ void dv_emit2(const float* __restrict__ points,
                         const unsigned* __restrict__ offsets,
                         const unsigned* __restrict__ perm,
                         const Meta* __restrict__ meta,
                         float* __restrict__ out_mean,
                         float* __restrict__ out_coords) {
    int b = blockIdx.x, t = threadIdx.x;
    int base = b * 1024 + t * 4;
    uint4 o4 = ((const uint4*)offsets)[b * 256 + t];
    unsigned o[5];
    o[0] = o4.x; o[1] = o4.y; o[2] = o4.z; o[3] = o4.w;
    o[4] = offsets[base + 4];
    int c[4], pre[4], mycount = 0;
#pragma unroll
    for (int j = 0; j < 4; ++j) {
        c[j] = (int)(o[j + 1] - o[j]);
        pre[j] = mycount;
        mycount += (c[j] > 0) ? 1 : 0;
    }
    __shared__ int sm[256];
    sm[t] = mycount;
    __syncthreads();
    for (int off = 1; off < 256; off <<= 1) {
        int v = (t >= off) ? sm[t - off] : 0;
        __syncthreads();
        sm[t] += v;
        __syncthreads();
    }
    int rank0 = (int)meta->blockRankOffs[b] + (sm[t] - mycount);
#pragma unroll
    for (int j = 0; j < 4; ++j) {
        if (c[j] > 0) {
            float s0 = 0.f, s1 = 0.f, s2 = 0.f, s3 = 0.f,
                  s4 = 0.f, s5 = 0.f, s6 = 0.f;
            for (unsigned k = o[j]; k < o[j + 1]; ++k) {
                unsigned idx = perm[k];
                const float* p = points + (size_t)idx * 7;
                s0 += p[0]; s1 += p[1]; s2 += p[2]; s3 += p[3];
                s4 += p[4]; s5 += p[5]; s6 += p[6];
            }
            int r = rank0 + pre[j];
            int v = base + j;
            float inv = 1.0f / (float)c[j];
            float* m = out_mean + (size_t)r * 7;
            m[0] = s0 * inv; m[1] = s1 * inv; m[2] = s2 * inv;
            m[3] = s3 * inv; m[4] = s4 * inv; m[5] = s5 * inv;
            m[6] = s6 * inv;
            float* cd = out_coords + (size_t)r * 3;
            cd[0] = (float)(v >> 12);
            cd[1] = (float)((v >> 6) & 63);
            cd[2] = (float)(v & 63);
        }
    }
}

// ======================= launch =============================================
extern "C" void kernel_launch(void* const* d_in, const int* in_sizes, int n_in,
                              void* d_out, int out_size, void* d_ws, size_t ws_size,
                              hipStream_t stream) {
    const float* points = (const float*)d_in[0];
    const int*   gi     = (const int*)d_in[1];
    int n = in_sizes[0] / 7;   // 4,000,000

    float* out_mean   = (float*)d_out;
    float* out_coords = (float*)d_out + (size_t)n * 7;

    int threads = 256;
    int nb1 = (n + PPB - 1) / PPB;

    // radix-path workspace need
    size_t recsB = (size_t)n * 8 * sizeof(float);            // 128 MiB
    size_t bhB   = (size_t)nb1 * NB * sizeof(unsigned);      // ~2 MB
    size_t accB  = (size_t)NB * VPB * 8 * sizeof(float);     // 8 MiB
    size_t need  = recsB + bhB + (NB + 1) * 4 /*bucketBase*/ +
                   accB + NB * 4 /*bucketCount*/ + NB * 4 /*occCount*/ +
                   (NB + 1) * 4 /*rankBase (+nUnique)*/ + 256;

    size_t fillChunks = (size_t)n * 7 / 4 + (size_t)n * 3 / 4;
    int fillBlocks = (int)((fillChunks + threads - 1) / threads);

    if (ws_size >= need) {
        // ---------------- radix fat-record path ----------------
        char* w = (char*)d_ws;
        float*    recs        = (float*)w;                 w += recsB;
        unsigned* blockHist   = (unsigned*)w;              w += bhB;
        unsigned* bucketCount = (unsigned*)w;              w += NB * 4;
        unsigned* bucketBase  = (unsigned*)w;              w += (NB + 1) * 4;
        unsigned* occCount    = (unsigned*)w;              w += NB * 4;
        unsigned* rankBase    = (unsigned*)w;              w += (NB + 1) * 4;
        float*    accTable    = (float*)w;

        rx_hist<<<nb1, 256, 0, stream>>>(gi, n, blockHist);
        rx_bucketsum<<<NB, 256, 0, stream>>>(blockHist, nb1, bucketCount);
        rx_scan256<<<1, NB, 0, stream>>>(bucketCount, bucketBase);
        rx_blockscan<<<NB, 256, 0, stream>>>(blockHist, nb1, bucketBase);
        rx_scatter<<<nb1, 256, 0, stream>>>(gi, points, n, blockHist, recs);
        rx_accum<<<NB, 256, 0, stream>>>(recs, bucketBase, accTable, occCount);
        rx_scan256<<<1, NB, 0, stream>>>(occCount, rankBase);
        rx_emit<<<NB, 256, 0, stream>>>(accTable, rankBase, out_mean, out_coords);
        dv_fill<<<fillBlocks, threads, 0, stream>>>(rankBase + NB,
                                                    (float*)d_out, n);
    } else {
        // ---------------- fallback: round-3 path ----------------
        char* w = (char*)d_ws;
        unsigned*       perm    = (unsigned*)w;
        unsigned short* slots   = (unsigned short*)(w + (size_t)n * 4);
        unsigned*       offsets = (unsigned*)(w + (size_t)n * 4 + (size_t)n * 2);
        Meta*           meta    = (Meta*)((char*)offsets + (size_t)(NVOX + 4) * 4);

        hipMemsetAsync(offsets, 0, (size_t)(NVOX + 4) * 4, stream);

        int blocksN = (n + threads - 1) / threads;
        dv_count<<<blocksN, threads, 0, stream>>>(gi, n, offsets, slots);
        dv_bs1<<<NBLK, 256, 0, stream>>>(offsets, meta);
        dv_scan2<<<1, NBLK, 0, stream>>>(offsets, n, meta);
        dv_scan3<<<NBLK, 256, 0, stream>>>(offsets, meta);
        dv_scatter2<<<blocksN, threads, 0, stream>>>(gi, n, offsets, slots, perm);
        dv_emit2<<<NBLK, 256, 0, stream>>>(points, offsets, perm, meta,
                                           out_mean, out_coords);
        dv_fill<<<fillBlocks, threads, 0, stream>>>(&meta->nUnique,
                                                    (float*)d_out, n);
    }
}

// Round 5
// 556.005 us; speedup vs baseline: 3.2997x; 1.0211x over previous
//
#include <hip/hip_runtime.h>

#define NVOX 262144     // 64^3
#define NB   256        // buckets = top 8 bits of lin
#define VPB  1024       // voxels per bucket = low 10 bits
#define PPB  2048       // points per block in binning passes
#define CAP  7          // staged records per bucket per 256-point chunk
#define NBLK 256        // fallback voxel-walker blocks

// ======================= shared: padding fill ===============================
__global__ void dv_fill(const unsigned* __restrict__ nuP,
                        float* __restrict__ out, int n) {
    int nu = (int)*nuP;
    size_t meanChunks = (size_t)n * 7 / 4;
    size_t coordChunks = (size_t)n * 3 / 4;
    size_t total = meanChunks + coordChunks;
    size_t i = (size_t)blockIdx.x * blockDim.x + threadIdx.x;
    if (i >= total) return;
    float* mean = out;
    float* coords = out + (size_t)n * 7;
    if (i < meanChunks) {
        size_t base = i * 4, lim = (size_t)nu * 7;
        if (base >= lim) {
            *(float4*)(mean + base) = make_float4(0.f, 0.f, 0.f, 0.f);
        } else if (base + 4 > lim) {
            for (size_t k = lim; k < base + 4; ++k) mean[k] = 0.f;
        }
    } else {
        size_t base = (i - meanChunks) * 4, lim = (size_t)nu * 3;
        if (base >= lim) {
            *(float4*)(coords + base) = make_float4(-1.f, -1.f, -1.f, -1.f);
        } else if (base + 4 > lim) {
            for (size_t k = lim; k < base + 4; ++k) coords[k] = -1.f;
        }
    }
}

// ======================= RADIX (fat-record) PATH ============================
// P1: per-block LDS histogram over 256 buckets (coalesced global write)
__global__ void rx_hist(const int* __restrict__ gi, int n,
                        unsigned* __restrict__ blockHist) {
    __shared__ unsigned h[NB];
    int t = threadIdx.x, b = blockIdx.x;
    h[t] = 0;
    __syncthreads();
    int base = b * PPB;
#pragma unroll
    for (int k = 0; k < PPB / 256; ++k) {
        int i = base + k * 256 + t;
        if (i < n) {
            int g0 = gi[3 * i], g1 = gi[3 * i + 1];
            atomicAdd(&h[(g0 << 2) | (g1 >> 4)], 1u);
        }
    }
    __syncthreads();
    blockHist[(size_t)b * NB + t] = h[t];
}

// P2a: per-bucket totals (one block per bucket)
__global__ void rx_bucketsum(const unsigned* __restrict__ blockHist, int nb1,
                             unsigned* __restrict__ bucketCount) {
    int bk = blockIdx.x, t = threadIdx.x;
    unsigned s = 0;
    for (int blk = t; blk < nb1; blk += 256) s += blockHist[(size_t)blk * NB + bk];
    __shared__ unsigned sm[256];
    sm[t] = s;
    __syncthreads();
    for (int off = 128; off > 0; off >>= 1) {
        if (t < off) sm[t] += sm[t + off];
        __syncthreads();
    }
    if (t == 0) bucketCount[bk] = sm[0];
}

// P2b / P5: exclusive scan of 256 values; out[256] = total
__global__ void rx_scan256(const unsigned* __restrict__ in,
                           unsigned* __restrict__ out) {
    __shared__ unsigned sm[NB];
    int t = threadIdx.x;
    unsigned mine = in[t];
    sm[t] = mine;
    __syncthreads();
    for (int off = 1; off < NB; off <<= 1) {
        unsigned v = (t >= off) ? sm[t - off] : 0u;
        __syncthreads();
        sm[t] += v;
        __syncthreads();
    }
    out[t] = sm[t] - mine;
    if (t == NB - 1) out[NB] = sm[t];
}

// P2c: per-bucket exclusive scan over block hists (in place, + bucketBase)
__global__ void rx_blockscan(unsigned* __restrict__ blockHist, int nb1,
                             const unsigned* __restrict__ bucketBase) {
    int bk = blockIdx.x, t = threadIdx.x;
    __shared__ unsigned sm[256];
    __shared__ unsigned carry;
    if (t == 0) carry = bucketBase[bk];
    __syncthreads();
    for (int chunk = 0; chunk * 256 < nb1; ++chunk) {
        int blk = chunk * 256 + t;
        unsigned v = (blk < nb1) ? blockHist[(size_t)blk * NB + bk] : 0u;
        sm[t] = v;
        __syncthreads();
        for (int off = 1; off < 256; off <<= 1) {
            unsigned u = (t >= off) ? sm[t - off] : 0u;
            __syncthreads();
            sm[t] += u;
            __syncthreads();
        }
        if (blk < nb1) blockHist[(size_t)blk * NB + bk] = carry + sm[t] - v;
        __syncthreads();
        if (t == 255) carry += sm[255];
        __syncthreads();
    }
}

// P3: fat scatter with LDS staging — flush contiguous per-bucket 32B records
__global__ void __launch_bounds__(256) rx_scatter(
        const int* __restrict__ gi, const float* __restrict__ pts, int n,
        const unsigned* __restrict__ blockHist, float* __restrict__ recs) {
    __shared__ float stage[NB][CAP][8];     // 56 KB
    __shared__ unsigned stageCount[NB];
    __shared__ unsigned runNext[NB];
    int t = threadIdx.x, b = blockIdx.x;
    runNext[t] = blockHist[(size_t)b * NB + t];
    int base = b * PPB;
#pragma unroll 1
    for (int k = 0; k < PPB / 256; ++k) {
        stageCount[t] = 0;
        __syncthreads();
        int i = base + k * 256 + t;
        if (i < n) {
            int g0 = gi[3 * i], g1 = gi[3 * i + 1], g2 = gi[3 * i + 2];
            int bk = (g0 << 2) | (g1 >> 4);
            unsigned sub = (unsigned)(((g1 & 15) << 6) | g2);
            const float* p = pts + (size_t)i * 7;
            float r0 = p[0], r1 = p[1], r2 = p[2], r3 = p[3];
            float r4 = p[4], r5 = p[5], r6 = p[6];
            unsigned pos = atomicAdd(&stageCount[bk], 1u);
            if (pos < CAP) {
                float4* s4 = (float4*)stage[bk][pos];
                s4[0] = make_float4(r0, r1, r2, r3);
                s4[1] = make_float4(r4, r5, r6, __uint_as_float(sub));
            } else {  // rare overflow: direct scattered write (unique slot)
                float4* d = (float4*)(recs + (size_t)(runNext[bk] + pos) * 8);
                d[0] = make_float4(r0, r1, r2, r3);
                d[1] = make_float4(r4, r5, r6, __uint_as_float(sub));
            }
        }
        __syncthreads();
        // flush: 8 lanes per bucket -> contiguous 32B-record bursts
        int r8 = t & 7, bgrp = t >> 3;      // bgrp in [0,32)
#pragma unroll
        for (int it = 0; it < 8; ++it) {
            int bk2 = it * 32 + bgrp;
            unsigned cnt = stageCount[bk2];
            unsigned c = cnt < CAP ? cnt : CAP;
            if ((unsigned)r8 < c) {
                const float4* s4 = (const float4*)stage[bk2][r8];
                float4 lo = s4[0], hi = s4[1];
                float4* d = (float4*)(recs + (size_t)(runNext[bk2] + r8) * 8);
                d[0] = lo;
                d[1] = hi;
            }
        }
        __syncthreads();
        runNext[t] += stageCount[t];
        // (next loop-top write to stageCount[t] is by this same thread t)
    }
}

// P4: per-bucket LDS accumulation, 1024 threads (16 waves) + prefetch
__global__ void __launch_bounds__(1024) rx_accum(
        const float* __restrict__ recs,
        const unsigned* __restrict__ bucketBase,
        float* __restrict__ accTable, unsigned* __restrict__ occCount) {
    __shared__ float acc[VPB * 9];   // 36 KB, stride-9 vs bank conflicts
    __shared__ unsigned smw[16];
    int t = threadIdx.x, bk = blockIdx.x;
    for (int k = t; k < VPB * 9; k += 1024) acc[k] = 0.f;
    __syncthreads();
    unsigned s = bucketBase[bk], e = bucketBase[bk + 1];
    unsigned i = s + t;
    bool have = (i < e);
    float4 r0, r1;
    if (have) {
        const float4* r = (const float4*)(recs + (size_t)i * 8);
        r0 = r[0]; r1 = r[1];
    }
    while (have) {
        unsigned nx = i + 1024;
        bool nh = (nx < e);
        float4 n0, n1;
        if (nh) {   // prefetch next record before the dependent LDS atomics
            const float4* r = (const float4*)(recs + (size_t)nx * 8);
            n0 = r[0]; n1 = r[1];
        }
        unsigned sub = __float_as_uint(r1.w);
        float* a = acc + sub * 9;
        atomicAdd(a + 0, r0.x); atomicAdd(a + 1, r0.y);
        atomicAdd(a + 2, r0.z); atomicAdd(a + 3, r0.w);
        atomicAdd(a + 4, r1.x); atomicAdd(a + 5, r1.y);
        atomicAdd(a + 6, r1.z); atomicAdd(a + 7, 1.0f);
        i = nx; r0 = n0; r1 = n1; have = nh;
    }
    __syncthreads();
    int v = t;   // 1024 threads, 1024 voxels
    float c = acc[v * 9 + 7];
    float4* o = (float4*)(accTable + ((size_t)bk * VPB + v) * 8);
    o[0] = make_float4(acc[v * 9 + 0], acc[v * 9 + 1],
                       acc[v * 9 + 2], acc[v * 9 + 3]);
    o[1] = make_float4(acc[v * 9 + 4], acc[v * 9 + 5],
                       acc[v * 9 + 6], c);
    unsigned long long m = __ballot(c > 0.f);
    if ((t & 63) == 0) smw[t >> 6] = (unsigned)__popcll(m);
    __syncthreads();
    if (t == 0) {
        unsigned occ = 0;
#pragma unroll
        for (int w = 0; w < 16; ++w) occ += smw[w];
        occCount[bk] = occ;
    }
}

// P6: emit compacted means + coords from accTable
__global__ void rx_emit(const float* __restrict__ accTable,
                        const unsigned* __restrict__ rankBase,
                        float* __restrict__ out_mean,
                        float* __restrict__ out_coords) {
    int bk = blockIdx.x, t = threadIdx.x;
    float row[4][8];
    int pre[4], mycount = 0;
#pragma unroll
    for (int j = 0; j < 4; ++j) {
        int v = t * 4 + j;
        const float4* a = (const float4*)(accTable + ((size_t)bk * VPB + v) * 8);
        float4 r0 = a[0], r1 = a[1];
        row[j][0] = r0.x; row[j][1] = r0.y; row[j][2] = r0.z; row[j][3] = r0.w;
        row[j][4] = r1.x; row[j][5] = r1.y; row[j][6] = r1.z; row[j][7] = r1.w;
        pre[j] = mycount;
        mycount += (row[j][7] > 0.f) ? 1 : 0;
    }
    __shared__ int sm[256];
    sm[t] = mycount;
    __syncthreads();
    for (int off = 1; off < 256; off <<= 1) {
        int v = (t >= off) ? sm[t - off] : 0;
        __syncthreads();
        sm[t] += v;
        __syncthreads();
    }
    int rank0 = (int)rankBase[bk] + (sm[t] - mycount);
#pragma unroll
    for (int j = 0; j < 4; ++j) {
        if (row[j][7] > 0.f) {
            int r = rank0 + pre[j];
            int lin = (bk << 10) | (t * 4 + j);
            float inv = 1.0f / row[j][7];
            float* m = out_mean + (size_t)r * 7;
#pragma unroll
            for (int k = 0; k < 7; ++k) m[k] = row[j][k] * inv;
            float* cd = out_coords + (size_t)r * 3;
            cd[0] = (float)(lin >> 12);
            cd[1] = (float)((lin >> 6) & 63);
            cd[2] = (float)(lin & 63);
        }
    }
}

// ======================= FALLBACK PATH (round-3, proven) ====================
struct Meta {
    unsigned blockSums[NBLK];
    unsigned blockFlagSums[NBLK];
    unsigned blockOffs[NBLK];
    unsigned blockRankOffs[NBLK];
    unsigned nUnique;
};

__global__ void dv_count(const int* __restrict__ gi, int n,
                         unsigned* __restrict__ counts,
                         unsigned short* __restrict__ slots) {
    int i = blockIdx.x * blockDim.x + threadIdx.x;
    if (i >= n) return;
    int lin = (gi[3 * i] << 12) | (gi[3 * i + 1] << 6) | gi[3 * i + 2];
    unsigned s = atomicAdd(&counts[lin], 1u);
    slots[i] = (unsigned short)s;
}

__global__ void dv_bs1(const unsigned* __restrict__ counts,
                       Meta* __restrict__ meta) {
    int b = blockIdx.x, t = threadIdx.x;
    uint4 c = ((const uint4*)(counts + (size_t)b * 1024))[t];
    unsigned cs = c.x + c.y + c.z + c.w;
    unsigned fs = (c.x > 0) + (c.y > 0) + (c.z > 0) + (c.w > 0);
    __shared__ unsigned smC[256], smF[256];
    smC[t] = cs; smF[t] = fs;
    __syncthreads();
    for (int off = 128; off > 0; off >>= 1) {
        if (t < off) { smC[t] += smC[t + off]; smF[t] += smF[t + off]; }
        __syncthreads();
    }
    if (t == 0) { meta->blockSums[b] = smC[0]; meta->blockFlagSums[b] = smF[0]; }
}

__global__ void dv_scan2(unsigned* __restrict__ offsets, int n,
                         Meta* __restrict__ meta) {
    __shared__ unsigned smC[NBLK], smF[NBLK];
    int t = threadIdx.x;
    unsigned c = meta->blockSums[t], f = meta->blockFlagSums[t];
    smC[t] = c; smF[t] = f;
    __syncthreads();
    for (int off = 1; off < NBLK; off <<= 1) {
        unsigned vc = (t >= off) ? smC[t - off] : 0u;
        unsigned vf = (t >= off) ? smF[t - off] : 0u;
        __syncthreads();
        smC[t] += vc; smF[t] += vf;
        __syncthreads();
    }
    meta->blockOffs[t] = smC[t] - c;
    meta->blockRankOffs[t] = smF[t] - f;
    if (t == NBLK - 1) { meta->nUnique = smF[t]; offsets[NVOX] = (unsigned)n; }
}

__global__ void dv_scan3(unsigned* __restrict__ counts,
                         const Meta* __restrict__ meta) {
    int b = blockIdx.x, t = threadIdx.x;
    uint4 c = ((const uint4*)(counts + (size_t)b * 1024))[t];
    unsigned mysum = c.x + c.y + c.z + c.w;
    __shared__ unsigned sm[256];
    sm[t] = mysum;
    __syncthreads();
    for (int off = 1; off < 256; off <<= 1) {
        unsigned v = (t >= off) ? sm[t - off] : 0u;
        __syncthreads();
        sm[t] += v;
        __syncthreads();
    }
    unsigned base = meta->blockOffs[b] + sm[t] - mysum;
    uint4 o;
    o.x = base;
    o.y = base + c.x;
    o.z = o.y + c.y;
    o.w = o.z + c.z;
    ((uint4*)(counts + (size_t)b * 1024))[t] = o;
}

__global__ void dv_scatter2(const int* __restrict__ gi, int n,
                            const unsigned* __restrict__ offsets,
                            const unsigned short* __restrict__ slots,
                            unsigned* __restrict__ perm) {
    int i = blockIdx.x * blockDim.x + threadIdx.x;
    if (i >= n) return;
    int lin = (gi[3 * i] << 12) | (gi[3 * i + 1] << 6) | gi[3 * i + 2];
    perm[offsets[lin] + (unsigned)slots[i]] = (unsigned)i;
}

__global__ void dv_emit2(const float* __restrict__ points,
                         const unsigned* __restrict__ offsets,
                         const unsigned* __restrict__ perm,
                         const Meta* __restrict__ meta,
                         float* __restrict__ out_mean,
                         float* __restrict__ out_coords) {
    int b = blockIdx.x, t = threadIdx.x;
    int base = b * 1024 + t * 4;
    uint4 o4 = ((const uint4*)offsets)[b * 256 + t];
    unsigned o[5];
    o[0] = o4.x; o[1] = o4.y; o[2] = o4.z; o[3] = o4.w;
    o[4] = offsets[base + 4];
    int c[4], pre[4], mycount = 0;
#pragma unroll
    for (int j = 0; j < 4; ++j) {
        c[j] = (int)(o[j + 1] - o[j]);
        pre[j] = mycount;
        mycount += (c[j] > 0) ? 1 : 0;
    }
    __shared__ int sm[256];
    sm[t] = mycount;
    __syncthreads();
    for (int off = 1; off < 256; off <<= 1) {
        int v = (t >= off) ? sm[t - off] : 0;
        __syncthreads();
        sm[t] += v;
        __syncthreads();
    }
    int rank0 = (int)meta->blockRankOffs[b] + (sm[t] - mycount);
#pragma unroll
    for (int j = 0; j < 4; ++j) {
        if (c[j] > 0) {
            float s0 = 0.f, s1 = 0.f, s2 = 0.f, s3 = 0.f,
                  s4 = 0.f, s5 = 0.f, s6 = 0.f;
            for (unsigned k = o[j]; k < o[j + 1]; ++k) {
                unsigned idx = perm[k];
                const float* p = points + (size_t)idx * 7;
                s0 += p[0]; s1 += p[1]; s2 += p[2]; s3 += p[3];
                s4 += p[4]; s5 += p[5]; s6 += p[6];
            }
            int r = rank0 + pre[j];
            int v = base + j;
            float inv = 1.0f / (float)c[j];
            float* m = out_mean + (size_t)r * 7;
            m[0] = s0 * inv; m[1] = s1 * inv; m[2] = s2 * inv;
            m[3] = s3 * inv; m[4] = s4 * inv; m[5] = s5 * inv;
            m[6] = s6 * inv;
            float* cd = out_coords + (size_t)r * 3;
            cd[0] = (float)(v >> 12);
            cd[1] = (float)((v >> 6) & 63);
            cd[2] = (float)(v & 63);
        }
    }
}

// ======================= launch =============================================
extern "C" void kernel_launch(void* const* d_in, const int* in_sizes, int n_in,
                              void* d_out, int out_size, void* d_ws, size_t ws_size,
                              hipStream_t stream) {
    const float* points = (const float*)d_in[0];
    const int*   gi     = (const int*)d_in[1];
    int n = in_sizes[0] / 7;   // 4,000,000

    float* out_mean   = (float*)d_out;
    float* out_coords = (float*)d_out + (size_t)n * 7;

    int threads = 256;
    int nb1 = (n + PPB - 1) / PPB;

    size_t recsB = (size_t)n * 8 * sizeof(float);            // 128 MiB
    size_t bhB   = (size_t)nb1 * NB * sizeof(unsigned);      // ~2 MB
    size_t accB  = (size_t)NB * VPB * 8 * sizeof(float);     // 8 MiB
    size_t need  = recsB + bhB + (NB + 1) * 4 + accB + NB * 4 + NB * 4 +
                   (NB + 1) * 4 + 256;

    size_t fillChunks = (size_t)n * 7 / 4 + (size_t)n * 3 / 4;
    int fillBlocks = (int)((fillChunks + threads - 1) / threads);

    if (ws_size >= need) {
        char* w = (char*)d_ws;
        float*    recs        = (float*)w;                 w += recsB;
        unsigned* blockHist   = (unsigned*)w;              w += bhB;
        unsigned* bucketCount = (unsigned*)w;              w += NB * 4;
        unsigned* bucketBase  = (unsigned*)w;              w += (NB + 1) * 4;
        unsigned* occCount    = (unsigned*)w;              w += NB * 4;
        unsigned* rankBase    = (unsigned*)w;              w += (NB + 1) * 4;
        float*    accTable    = (float*)w;

        rx_hist<<<nb1, 256, 0, stream>>>(gi, n, blockHist);
        rx_bucketsum<<<NB, 256, 0, stream>>>(blockHist, nb1, bucketCount);
        rx_scan256<<<1, NB, 0, stream>>>(bucketCount, bucketBase);
        rx_blockscan<<<NB, 256, 0, stream>>>(blockHist, nb1, bucketBase);
        rx_scatter<<<nb1, 256, 0, stream>>>(gi, points, n, blockHist, recs);
        rx_accum<<<NB, 1024, 0, stream>>>(recs, bucketBase, accTable, occCount);
        rx_scan256<<<1, NB, 0, stream>>>(occCount, rankBase);
        rx_emit<<<NB, 256, 0, stream>>>(accTable, rankBase, out_mean, out_coords);
        dv_fill<<<fillBlocks, threads, 0, stream>>>(rankBase + NB,
                                                    (float*)d_out, n);
    } else {
        char* w = (char*)d_ws;
        unsigned*       perm    = (unsigned*)w;
        unsigned short* slots   = (unsigned short*)(w + (size_t)n * 4);
        unsigned*       offsets = (unsigned*)(w + (size_t)n * 4 + (size_t)n * 2);
        Meta*           meta    = (Meta*)((char*)offsets + (size_t)(NVOX + 4) * 4);

        hipMemsetAsync(offsets, 0, (size_t)(NVOX + 4) * 4, stream);

        int blocksN = (n + threads - 1) / threads;
        dv_count<<<blocksN, threads, 0, stream>>>(gi, n, offsets, slots);
        dv_bs1<<<NBLK, 256, 0, stream>>>(offsets, meta);
        dv_scan2<<<1, NBLK, 0, stream>>>(offsets, n, meta);
        dv_scan3<<<NBLK, 256, 0, stream>>>(offsets, meta);
        dv_scatter2<<<blocksN, threads, 0, stream>>>(gi, n, offsets, slots, perm);
        dv_emit2<<<NBLK, 256, 0, stream>>>(points, offsets, perm, meta,
                                           out_mean, out_coords);
        dv_fill<<<fillBlocks, threads, 0, stream>>>(&meta->nUnique,
                                                    (float*)d_out, n);
    }
}

// Round 6
// 448.497 us; speedup vs baseline: 4.0906x; 1.2397x over previous
//
#include <hip/hip_runtime.h>

#define NVOX 262144     // 64^3
#define NB   256        // buckets = top 8 bits of lin
#define VPB  1024       // voxels per bucket = low 10 bits
#define PPB  2048       // points per block in binning passes
#define CAP  7          // staged records per bucket per 1024-point chunk
#define CHUNK 16384     // records per accum sorting chunk (u16 perm)
#define NBLK 256        // fallback voxel-walker blocks

// ======================= shared: padding fill ===============================
__global__ void dv_fill(const unsigned* __restrict__ nuP,
                        float* __restrict__ out, int n) {
    int nu = (int)*nuP;
    size_t meanChunks = (size_t)n * 7 / 4;
    size_t coordChunks = (size_t)n * 3 / 4;
    size_t total = meanChunks + coordChunks;
    size_t i = (size_t)blockIdx.x * blockDim.x + threadIdx.x;
    if (i >= total) return;
    float* mean = out;
    float* coords = out + (size_t)n * 7;
    if (i < meanChunks) {
        size_t base = i * 4, lim = (size_t)nu * 7;
        if (base >= lim) {
            *(float4*)(mean + base) = make_float4(0.f, 0.f, 0.f, 0.f);
        } else if (base + 4 > lim) {
            for (size_t k = lim; k < base + 4; ++k) mean[k] = 0.f;
        }
    } else {
        size_t base = (i - meanChunks) * 4, lim = (size_t)nu * 3;
        if (base >= lim) {
            *(float4*)(coords + base) = make_float4(-1.f, -1.f, -1.f, -1.f);
        } else if (base + 4 > lim) {
            for (size_t k = lim; k < base + 4; ++k) coords[k] = -1.f;
        }
    }
}

// ======================= RADIX (fat-record) PATH ============================
// P1: per-block LDS histogram over 256 buckets (coalesced global write)
__global__ void rx_hist(const int* __restrict__ gi, int n,
                        unsigned* __restrict__ blockHist) {
    __shared__ unsigned h[NB];
    int t = threadIdx.x, b = blockIdx.x;
    h[t] = 0;
    __syncthreads();
    int base = b * PPB;
#pragma unroll
    for (int k = 0; k < PPB / 256; ++k) {
        int i = base + k * 256 + t;
        if (i < n) {
            int g0 = gi[3 * i], g1 = gi[3 * i + 1];
            atomicAdd(&h[(g0 << 2) | (g1 >> 4)], 1u);
        }
    }
    __syncthreads();
    blockHist[(size_t)b * NB + t] = h[t];
}

// P2a: per-bucket totals (one block per bucket)
__global__ void rx_bucketsum(const unsigned* __restrict__ blockHist, int nb1,
                             unsigned* __restrict__ bucketCount) {
    int bk = blockIdx.x, t = threadIdx.x;
    unsigned s = 0;
    for (int blk = t; blk < nb1; blk += 256) s += blockHist[(size_t)blk * NB + bk];
    __shared__ unsigned sm[256];
    sm[t] = s;
    __syncthreads();
    for (int off = 128; off > 0; off >>= 1) {
        if (t < off) sm[t] += sm[t + off];
        __syncthreads();
    }
    if (t == 0) bucketCount[bk] = sm[0];
}

// P2b / P5: exclusive scan of 256 values; out[256] = total
__global__ void rx_scan256(const unsigned* __restrict__ in,
                           unsigned* __restrict__ out) {
    __shared__ unsigned sm[NB];
    int t = threadIdx.x;
    unsigned mine = in[t];
    sm[t] = mine;
    __syncthreads();
    for (int off = 1; off < NB; off <<= 1) {
        unsigned v = (t >= off) ? sm[t - off] : 0u;
        __syncthreads();
        sm[t] += v;
        __syncthreads();
    }
    out[t] = sm[t] - mine;
    if (t == NB - 1) out[NB] = sm[t];
}

// P2c: per-bucket exclusive scan over block hists (in place, + bucketBase)
__global__ void rx_blockscan(unsigned* __restrict__ blockHist, int nb1,
                             const unsigned* __restrict__ bucketBase) {
    int bk = blockIdx.x, t = threadIdx.x;
    __shared__ unsigned sm[256];
    __shared__ unsigned carry;
    if (t == 0) carry = bucketBase[bk];
    __syncthreads();
    for (int chunk = 0; chunk * 256 < nb1; ++chunk) {
        int blk = chunk * 256 + t;
        unsigned v = (blk < nb1) ? blockHist[(size_t)blk * NB + bk] : 0u;
        sm[t] = v;
        __syncthreads();
        for (int off = 1; off < 256; off <<= 1) {
            unsigned u = (t >= off) ? sm[t - off] : 0u;
            __syncthreads();
            sm[t] += u;
            __syncthreads();
        }
        if (blk < nb1) blockHist[(size_t)blk * NB + bk] = carry + sm[t] - v;
        __syncthreads();
        if (t == 255) carry += sm[255];
        __syncthreads();
    }
}

// P3: fat scatter, LDS-staged; 1024-pt chunks -> avg 4 recs/bucket/flush
__global__ void __launch_bounds__(256) rx_scatter(
        const int* __restrict__ gi, const float* __restrict__ pts, int n,
        const unsigned* __restrict__ blockHist, float* __restrict__ recs) {
    __shared__ float stage[NB][CAP][8];     // 56 KB
    __shared__ unsigned stageCount[NB];
    __shared__ unsigned runNext[NB];
    int t = threadIdx.x, b = blockIdx.x;
    runNext[t] = blockHist[(size_t)b * NB + t];
    int base = b * PPB;
#pragma unroll 1
    for (int chunk = 0; chunk < PPB / 1024; ++chunk) {
        stageCount[t] = 0;
        __syncthreads();
        int cb = base + chunk * 1024;
#pragma unroll
        for (int q = 0; q < 4; ++q) {
            int i = cb + q * 256 + t;
            if (i < n) {
                int g0 = gi[3 * i], g1 = gi[3 * i + 1], g2 = gi[3 * i + 2];
                int bk = (g0 << 2) | (g1 >> 4);
                unsigned sub = (unsigned)(((g1 & 15) << 6) | g2);
                const float* p = pts + (size_t)i * 7;
                float r0 = p[0], r1 = p[1], r2 = p[2], r3 = p[3];
                float r4 = p[4], r5 = p[5], r6 = p[6];
                unsigned pos = atomicAdd(&stageCount[bk], 1u);
                if (pos < CAP) {
                    float4* s4 = (float4*)stage[bk][pos];
                    s4[0] = make_float4(r0, r1, r2, r3);
                    s4[1] = make_float4(r4, r5, r6, __uint_as_float(sub));
                } else {  // ~2% overflow: direct scattered write (unique slot)
                    float4* d = (float4*)(recs + (size_t)(runNext[bk] + pos) * 8);
                    d[0] = make_float4(r0, r1, r2, r3);
                    d[1] = make_float4(r4, r5, r6, __uint_as_float(sub));
                }
            }
        }
        __syncthreads();
        // flush: 8 lanes per bucket -> contiguous 32B-record bursts (<=224B)
        int r8 = t & 7, bgrp = t >> 3;      // bgrp in [0,32)
#pragma unroll
        for (int it = 0; it < 8; ++it) {
            int bk2 = it * 32 + bgrp;
            unsigned cnt = stageCount[bk2];
            unsigned c = cnt < CAP ? cnt : CAP;
            if ((unsigned)r8 < c) {
                const float4* s4 = (const float4*)stage[bk2][r8];
                float4 lo = s4[0], hi = s4[1];
                float4* d = (float4*)(recs + (size_t)(runNext[bk2] + r8) * 8);
                d[0] = lo;
                d[1] = hi;
            }
        }
        __syncthreads();
        runNext[t] += stageCount[t];
    }
}

// P4: per-bucket in-LDS counting sort (2 LDS atomics/record) + register accum
__global__ void __launch_bounds__(1024) rx_accum(
        const float* __restrict__ recs,
        const unsigned* __restrict__ bucketBase,
        float* __restrict__ accTable, unsigned* __restrict__ occCount) {
    __shared__ unsigned off[VPB];           // hist -> offsets -> cursors
    __shared__ unsigned short perm[CHUNK];  // 32 KB
    __shared__ unsigned smw[16];
    int t = threadIdx.x, bk = blockIdx.x;
    unsigned s = bucketBase[bk], e = bucketBase[bk + 1];
    float a0 = 0.f, a1 = 0.f, a2 = 0.f, a3 = 0.f,
          a4 = 0.f, a5 = 0.f, a6 = 0.f, cf = 0.f;
    for (unsigned cs = s; cs < e; cs += CHUNK) {
        unsigned ce = cs + CHUNK < e ? cs + CHUNK : e;
        off[t] = 0;
        __syncthreads();
        // phase A: histogram of sub keys (1 LDS atomic/record); warms L2
        for (unsigned i = cs + t; i < ce; i += 1024)
            atomicAdd(&off[__float_as_uint(recs[(size_t)i * 8 + 7])], 1u);
        __syncthreads();
        unsigned mine = off[t];
        // phase B: inclusive scan -> exclusive starts (Hillis-Steele)
        for (int d = 1; d < 1024; d <<= 1) {
            unsigned v = (t >= d) ? off[t - d] : 0u;
            __syncthreads();
            off[t] += v;
            __syncthreads();
        }
        off[t] -= mine;   // own slot; all cross-reads done
        __syncthreads();
        // phase C: rank (1 LDS atomic/record) + scatter u16 index into perm
        for (unsigned i = cs + t; i < ce; i += 1024) {
            unsigned sub = __float_as_uint(recs[(size_t)i * 8 + 7]);
            unsigned pos = atomicAdd(&off[sub], 1u);
            perm[pos] = (unsigned short)(i - cs);
        }
        __syncthreads();
        // phase D: thread t owns voxel t — serial atomic-free gather (L2 hits)
        unsigned start = t ? off[t - 1] : 0u;   // off[v] is now end_v = start_{v+1}
        unsigned end = off[t];
        for (unsigned k = start; k < end; ++k) {
            const float4* r =
                (const float4*)(recs + ((size_t)cs + perm[k]) * 8);
            float4 lo = r[0], hi = r[1];
            a0 += lo.x; a1 += lo.y; a2 += lo.z; a3 += lo.w;
            a4 += hi.x; a5 += hi.y; a6 += hi.z; cf += 1.f;
        }
        __syncthreads();   // before off/perm reuse next chunk
    }
    float4* o = (float4*)(accTable + ((size_t)bk * VPB + t) * 8);
    o[0] = make_float4(a0, a1, a2, a3);
    o[1] = make_float4(a4, a5, a6, cf);
    unsigned long long m = __ballot(cf > 0.f);
    if ((t & 63) == 0) smw[t >> 6] = (unsigned)__popcll(m);
    __syncthreads();
    if (t == 0) {
        unsigned occ = 0;
#pragma unroll
        for (int w = 0; w < 16; ++w) occ += smw[w];
        occCount[bk] = occ;
    }
}

// P6: emit compacted means + coords from accTable
__global__ void rx_emit(const float* __restrict__ accTable,
                        const unsigned* __restrict__ rankBase,
                        float* __restrict__ out_mean,
                        float* __restrict__ out_coords) {
    int bk = blockIdx.x, t = threadIdx.x;
    float row[4][8];
    int pre[4], mycount = 0;
#pragma unroll
    for (int j = 0; j < 4; ++j) {
        int v = t * 4 + j;
        const float4* a = (const float4*)(accTable + ((size_t)bk * VPB + v) * 8);
        float4 r0 = a[0], r1 = a[1];
        row[j][0] = r0.x; row[j][1] = r0.y; row[j][2] = r0.z; row[j][3] = r0.w;
        row[j][4] = r1.x; row[j][5] = r1.y; row[j][6] = r1.z; row[j][7] = r1.w;
        pre[j] = mycount;
        mycount += (row[j][7] > 0.f) ? 1 : 0;
    }
    __shared__ int sm[256];
    sm[t] = mycount;
    __syncthreads();
    for (int off = 1; off < 256; off <<= 1) {
        int v = (t >= off) ? sm[t - off] : 0;
        __syncthreads();
        sm[t] += v;
        __syncthreads();
    }
    int rank0 = (int)rankBase[bk] + (sm[t] - mycount);
#pragma unroll
    for (int j = 0; j < 4; ++j) {
        if (row[j][7] > 0.f) {
            int r = rank0 + pre[j];
            int lin = (bk << 10) | (t * 4 + j);
            float inv = 1.0f / row[j][7];
            float* m = out_mean + (size_t)r * 7;
#pragma unroll
            for (int k = 0; k < 7; ++k) m[k] = row[j][k] * inv;
            float* cd = out_coords + (size_t)r * 3;
            cd[0] = (float)(lin >> 12);
            cd[1] = (float)((lin >> 6) & 63);
            cd[2] = (float)(lin & 63);
        }
    }
}

// ======================= FALLBACK PATH (round-3, proven) ====================
struct Meta {
    unsigned blockSums[NBLK];
    unsigned blockFlagSums[NBLK];
    unsigned blockOffs[NBLK];
    unsigned blockRankOffs[NBLK];
    unsigned nUnique;
};

__global__ void dv_count(const int* __restrict__ gi, int n,
                         unsigned* __restrict__ counts,
                         unsigned short* __restrict__ slots) {
    int i = blockIdx.x * blockDim.x + threadIdx.x;
    if (i >= n) return;
    int lin = (gi[3 * i] << 12) | (gi[3 * i + 1] << 6) | gi[3 * i + 2];
    unsigned s = atomicAdd(&counts[lin], 1u);
    slots[i] = (unsigned short)s;
}

__global__ void dv_bs1(const unsigned* __restrict__ counts,
                       Meta* __restrict__ meta) {
    int b = blockIdx.x, t = threadIdx.x;
    uint4 c = ((const uint4*)(counts + (size_t)b * 1024))[t];
    unsigned cs = c.x + c.y + c.z + c.w;
    unsigned fs = (c.x > 0) + (c.y > 0) + (c.z > 0) + (c.w > 0);
    __shared__ unsigned smC[256], smF[256];
    smC[t] = cs; smF[t] = fs;
    __syncthreads();
    for (int off = 128; off > 0; off >>= 1) {
        if (t < off) { smC[t] += smC[t + off]; smF[t] += smF[t + off]; }
        __syncthreads();
    }
    if (t == 0) { meta->blockSums[b] = smC[0]; meta->blockFlagSums[b] = smF[0]; }
}

__global__ void dv_scan2(unsigned* __restrict__ offsets, int n,
                         Meta* __restrict__ meta) {
    __shared__ unsigned smC[NBLK], smF[NBLK];
    int t = threadIdx.x;
    unsigned c = meta->blockSums[t], f = meta->blockFlagSums[t];
    smC[t] = c; smF[t] = f;
    __syncthreads();
    for (int off = 1; off < NBLK; off <<= 1) {
        unsigned vc = (t >= off) ? smC[t - off] : 0u;
        unsigned vf = (t >= off) ? smF[t - off] : 0u;
        __syncthreads();
        smC[t] += vc; smF[t] += vf;
        __syncthreads();
    }
    meta->blockOffs[t] = smC[t] - c;
    meta->blockRankOffs[t] = smF[t] - f;
    if (t == NBLK - 1) { meta->nUnique = smF[t]; offsets[NVOX] = (unsigned)n; }
}

__global__ void dv_scan3(unsigned* __restrict__ counts,
                         const Meta* __restrict__ meta) {
    int b = blockIdx.x, t = threadIdx.x;
    uint4 c = ((const uint4*)(counts + (size_t)b * 1024))[t];
    unsigned mysum = c.x + c.y + c.z + c.w;
    __shared__ unsigned sm[256];
    sm[t] = mysum;
    __syncthreads();
    for (int off = 1; off < 256; off <<= 1) {
        unsigned v = (t >= off) ? sm[t - off] : 0u;
        __syncthreads();
        sm[t] += v;
        __syncthreads();
    }
    unsigned base = meta->blockOffs[b] + sm[t] - mysum;
    uint4 o;
    o.x = base;
    o.y = base + c.x;
    o.z = o.y + c.y;
    o.w = o.z + c.z;
    ((uint4*)(counts + (size_t)b * 1024))[t] = o;
}

__global__ void dv_scatter2(const int* __restrict__ gi, int n,
                            const unsigned* __restrict__ offsets,
                            const unsigned short* __restrict__ slots,
                            unsigned* __restrict__ perm) {
    int i = blockIdx.x * blockDim.x + threadIdx.x;
    if (i >= n) return;
    int lin = (gi[3 * i] << 12) | (gi[3 * i + 1] << 6) | gi[3 * i + 2];
    perm[offsets[lin] + (unsigned)slots[i]] = (unsigned)i;
}

__global__ void dv_emit2(const float* __restrict__ points,
                         const unsigned* __restrict__ offsets,
                         const unsigned* __restrict__ perm,
                         const Meta* __restrict__ meta,
                         float* __restrict__ out_mean,
                         float* __restrict__ out_coords) {
    int b = blockIdx.x, t = threadIdx.x;
    int base = b * 1024 + t * 4;
    uint4 o4 = ((const uint4*)offsets)[b * 256 + t];
    unsigned o[5];
    o[0] = o4.x; o[1] = o4.y; o[2] = o4.z; o[3] = o4.w;
    o[4] = offsets[base + 4];
    int c[4], pre[4], mycount = 0;
#pragma unroll
    for (int j = 0; j < 4; ++j) {
        c[j] = (int)(o[j + 1] - o[j]);
        pre[j] = mycount;
        mycount += (c[j] > 0) ? 1 : 0;
    }
    __shared__ int sm[256];
    sm[t] = mycount;
    __syncthreads();
    for (int off = 1; off < 256; off <<= 1) {
        int v = (t >= off) ? sm[t - off] : 0;
        __syncthreads();
        sm[t] += v;
        __syncthreads();
    }
    int rank0 = (int)meta->blockRankOffs[b] + (sm[t] - mycount);
#pragma unroll
    for (int j = 0; j < 4; ++j) {
        if (c[j] > 0) {
            float s0 = 0.f, s1 = 0.f, s2 = 0.f, s3 = 0.f,
                  s4 = 0.f, s5 = 0.f, s6 = 0.f;
            for (unsigned k = o[j]; k < o[j + 1]; ++k) {
                unsigned idx = perm[k];
                const float* p = points + (size_t)idx * 7;
                s0 += p[0]; s1 += p[1]; s2 += p[2]; s3 += p[3];
                s4 += p[4]; s5 += p[5]; s6 += p[6];
            }
            int r = rank0 + pre[j];
            int v = base + j;
            float inv = 1.0f / (float)c[j];
            float* m = out_mean + (size_t)r * 7;
            m[0] = s0 * inv; m[1] = s1 * inv; m[2] = s2 * inv;
            m[3] = s3 * inv; m[4] = s4 * inv; m[5] = s5 * inv;
            m[6] = s6 * inv;
            float* cd = out_coords + (size_t)r * 3;
            cd[0] = (float)(v >> 12);
            cd[1] = (float)((v >> 6) & 63);
            cd[2] = (float)(v & 63);
        }
    }
}

// ======================= launch =============================================
extern "C" void kernel_launch(void* const* d_in, const int* in_sizes, int n_in,
                              void* d_out, int out_size, void* d_ws, size_t ws_size,
                              hipStream_t stream) {
    const float* points = (const float*)d_in[0];
    const int*   gi     = (const int*)d_in[1];
    int n = in_sizes[0] / 7;   // 4,000,000

    float* out_mean   = (float*)d_out;
    float* out_coords = (float*)d_out + (size_t)n * 7;

    int threads = 256;
    int nb1 = (n + PPB - 1) / PPB;

    size_t recsB = (size_t)n * 8 * sizeof(float);            // 128 MiB
    size_t bhB   = (size_t)nb1 * NB * sizeof(unsigned);      // ~2 MB
    size_t accB  = (size_t)NB * VPB * 8 * sizeof(float);     // 8 MiB
    size_t need  = recsB + bhB + (NB + 1) * 4 + accB + NB * 4 + NB * 4 +
                   (NB + 1) * 4 + 256;

    size_t fillChunks = (size_t)n * 7 / 4 + (size_t)n * 3 / 4;
    int fillBlocks = (int)((fillChunks + threads - 1) / threads);

    if (ws_size >= need) {
        char* w = (char*)d_ws;
        float*    recs        = (float*)w;                 w += recsB;
        unsigned* blockHist   = (unsigned*)w;              w += bhB;
        unsigned* bucketCount = (unsigned*)w;              w += NB * 4;
        unsigned* bucketBase  = (unsigned*)w;              w += (NB + 1) * 4;
        unsigned* occCount    = (unsigned*)w;              w += NB * 4;
        unsigned* rankBase    = (unsigned*)w;              w += (NB + 1) * 4;
        float*    accTable    = (float*)w;

        rx_hist<<<nb1, 256, 0, stream>>>(gi, n, blockHist);
        rx_bucketsum<<<NB, 256, 0, stream>>>(blockHist, nb1, bucketCount);
        rx_scan256<<<1, NB, 0, stream>>>(bucketCount, bucketBase);
        rx_blockscan<<<NB, 256, 0, stream>>>(blockHist, nb1, bucketBase);
        rx_scatter<<<nb1, 256, 0, stream>>>(gi, points, n, blockHist, recs);
        rx_accum<<<NB, 1024, 0, stream>>>(recs, bucketBase, accTable, occCount);
        rx_scan256<<<1, NB, 0, stream>>>(occCount, rankBase);
        rx_emit<<<NB, 256, 0, stream>>>(accTable, rankBase, out_mean, out_coords);
        dv_fill<<<fillBlocks, threads, 0, stream>>>(rankBase + NB,
                                                    (float*)d_out, n);
    } else {
        char* w = (char*)d_ws;
        unsigned*       perm    = (unsigned*)w;
        unsigned short* slots   = (unsigned short*)(w + (size_t)n * 4);
        unsigned*       offsets = (unsigned*)(w + (size_t)n * 4 + (size_t)n * 2);
        Meta*           meta    = (Meta*)((char*)offsets + (size_t)(NVOX + 4) * 4);

        hipMemsetAsync(offsets, 0, (size_t)(NVOX + 4) * 4, stream);

        int blocksN = (n + threads - 1) / threads;
        dv_count<<<blocksN, threads, 0, stream>>>(gi, n, offsets, slots);
        dv_bs1<<<NBLK, 256, 0, stream>>>(offsets, meta);
        dv_scan2<<<1, NBLK, 0, stream>>>(offsets, n, meta);
        dv_scan3<<<NBLK, 256, 0, stream>>>(offsets, meta);
        dv_scatter2<<<blocksN, threads, 0, stream>>>(gi, n, offsets, slots, perm);
        dv_emit2<<<NBLK, 256, 0, stream>>>(points, offsets, perm, meta,
                                           out_mean, out_coords);
        dv_fill<<<fillBlocks, threads, 0, stream>>>(&meta->nUnique,
                                                    (float*)d_out, n);
    }
}